// Round 3
// baseline (612.205 us; speedup 1.0000x reference)
//
#include <hip/hip_runtime.h>
#include <math.h>

// Volume dims (1,1,160,192,160) fp32
#define DD 160
#define HHH 192
#define WWW 160
constexpr int HW = HHH * WWW;          // 30720
constexpr int NV = DD * HHH * WWW;     // 4915200
constexpr int W4 = WWW / 4;            // 40
constexpr int HC = 6;                  // whsum5 H-chunk: 192/6 = 32 chunks
constexpr int DC = 5;                  // dcc D-chunk: 160/5 = 32 chunks

__global__ void zero_acc(double* __restrict__ acc) {
    if (threadIdx.x < 3) acc[threadIdx.x] = 0.0;
}

__device__ __forceinline__ float4 ldg4(const float* __restrict__ p, int idx, bool ok) {
    float4 z = make_float4(0.f, 0.f, 0.f, 0.f);
    return ok ? *(const float4*)(p + idx) : z;
}

// ---- Laplacian, 4 outputs/thread -------------------------------------------
__global__ void lap4(const float* __restrict__ a, const float* __restrict__ b,
                     float* __restrict__ oa, float* __restrict__ ob) {
    int t = blockIdx.x * 256 + threadIdx.x;
    int w = (t % W4) * 4;
    int h = (t / W4) % HHH;
    int d = t / (W4 * HHH);
    int idx = (d * HHH + h) * WWW + w;
    bool dok0 = d > 0, dok1 = d < DD - 1, hok0 = h > 0, hok1 = h < HHH - 1;

#pragma unroll
    for (int s = 0; s < 2; s++) {
        const float* p = s ? b : a;
        float* o = s ? ob : oa;
        float4 c = *(const float4*)(p + idx);
        float m1 = (w > 0) ? p[idx - 1] : 0.f;
        float p4 = (w + 4 < WWW) ? p[idx + 4] : 0.f;
        float4 dm = ldg4(p, idx - HW, dok0);
        float4 dp = ldg4(p, idx + HW, dok1);
        float4 hm = ldg4(p, idx - WWW, hok0);
        float4 hp = ldg4(p, idx + WWW, hok1);
        float4 r;
        r.x = 6.f * c.x - (m1 + c.y + dm.x + dp.x + hm.x + hp.x);
        r.y = 6.f * c.y - (c.x + c.z + dm.y + dp.y + hm.y + hp.y);
        r.z = 6.f * c.z - (c.y + c.w + dm.z + dp.z + hm.z + hp.z);
        r.w = 6.f * c.w - (c.z + p4 + dm.w + dp.w + hm.w + hp.w);
        *(float4*)(o + idx) = r;
    }
}

// ---- Sobel magnitude, 4 outputs/thread -------------------------------------
__global__ void sobel4(const float* __restrict__ a, const float* __restrict__ b,
                       float* __restrict__ oa, float* __restrict__ ob) {
    int t = blockIdx.x * 256 + threadIdx.x;
    int w = (t % W4) * 4;
    int h = (t / W4) % HHH;
    int d = t / (W4 * HHH);
    const float SM[3] = {1.f, 2.f, 1.f};
    const float GR[3] = {-1.f, 0.f, 1.f};

    float gxa[4] = {0, 0, 0, 0}, gya[4] = {0, 0, 0, 0}, gza[4] = {0, 0, 0, 0};
    float gxb[4] = {0, 0, 0, 0}, gyb[4] = {0, 0, 0, 0}, gzb[4] = {0, 0, 0, 0};

#pragma unroll
    for (int kd = -1; kd <= 1; kd++) {
#pragma unroll
        for (int kh = -1; kh <= 1; kh++) {
            int d2 = d + kd, h2 = h + kh;
            bool ok = ((unsigned)d2 < (unsigned)DD) && ((unsigned)h2 < (unsigned)HHH);
            int rb = (d2 * HHH + h2) * WWW;
            float wSMh = SM[kh + 1];
            float wGRd = GR[kd + 1];
            float wZ = SM[kd + 1] * GR[kh + 1];
            // A
            {
                float4 c = ldg4(a, rb + w, ok);
                float m1 = (ok && w > 0) ? a[rb + w - 1] : 0.f;
                float p4 = (ok && w + 4 < WWW) ? a[rb + w + 4] : 0.f;
                float xv[6] = {m1, c.x, c.y, c.z, c.w, p4};  // xv[j] = x[w+j-1]
#pragma unroll
                for (int k = 0; k < 4; k++) {
                    float gw = xv[k + 2] - xv[k];
                    float pw = xv[k] + xv[k + 1] + xv[k + 2];
                    float sw = pw + xv[k + 1];
                    gxa[k] += wSMh * gw;
                    gya[k] += wGRd * sw;
                    gza[k] += wZ * pw;
                }
            }
            // B
            {
                float4 c = ldg4(b, rb + w, ok);
                float m1 = (ok && w > 0) ? b[rb + w - 1] : 0.f;
                float p4 = (ok && w + 4 < WWW) ? b[rb + w + 4] : 0.f;
                float xv[6] = {m1, c.x, c.y, c.z, c.w, p4};
#pragma unroll
                for (int k = 0; k < 4; k++) {
                    float gw = xv[k + 2] - xv[k];
                    float pw = xv[k] + xv[k + 1] + xv[k + 2];
                    float sw = pw + xv[k + 1];
                    gxb[k] += wSMh * gw;
                    gyb[k] += wGRd * sw;
                    gzb[k] += wZ * pw;
                }
            }
        }
    }
    int idx = (d * HHH + h) * WWW + w;
    float4 ra, rbv;
    float* pa = (float*)&ra;
    float* pb = (float*)&rbv;
#pragma unroll
    for (int k = 0; k < 4; k++) {
        pa[k] = sqrtf(gxa[k] * gxa[k] + gya[k] * gya[k] + gza[k] * gza[k]);
        pb[k] = sqrtf(gxb[k] * gxb[k] + gyb[k] * gyb[k] + gzb[k] * gzb[k]);
    }
    *(float4*)(oa + idx) = ra;
    *(float4*)(ob + idx) = rbv;
}

// ---- Fused W+H box sums of 5 moments, 4 outputs/thread, sliding H window ----
__device__ __forceinline__ void rowq5(const float* __restrict__ a, const float* __restrict__ b,
                                      int rowbase, int w, float q[5][4]) {
    bool lo = (w >= 4);
    bool hi = (w + 7 < WWW);
    float4 x0 = ldg4(a, rowbase + w - 4, lo);
    float4 x1 = *(const float4*)(a + rowbase + w);
    float4 x2 = ldg4(a, rowbase + w + 4, hi);
    float4 y0 = ldg4(b, rowbase + w - 4, lo);
    float4 y1 = *(const float4*)(b + rowbase + w);
    float4 y2 = ldg4(b, rowbase + w + 4, hi);
    float x[12] = {x0.x, x0.y, x0.z, x0.w, x1.x, x1.y, x1.z, x1.w, x2.x, x2.y, x2.z, x2.w};
    float y[12] = {y0.x, y0.y, y0.z, y0.w, y1.x, y1.y, y1.z, y1.w, y2.x, y2.y, y2.z, y2.w};
    float s0 = 0, s1 = 0, s2 = 0, s3 = 0, s4 = 0;
#pragma unroll
    for (int j = 0; j < 9; j++) {
        s0 += x[j]; s1 += y[j];
        s2 += x[j] * x[j]; s3 += y[j] * y[j]; s4 += x[j] * y[j];
    }
    q[0][0] = s0; q[1][0] = s1; q[2][0] = s2; q[3][0] = s3; q[4][0] = s4;
#pragma unroll
    for (int k = 1; k < 4; k++) {
        q[0][k] = q[0][k - 1] + x[k + 8] - x[k - 1];
        q[1][k] = q[1][k - 1] + y[k + 8] - y[k - 1];
        q[2][k] = q[2][k - 1] + x[k + 8] * x[k + 8] - x[k - 1] * x[k - 1];
        q[3][k] = q[3][k - 1] + y[k + 8] * y[k + 8] - y[k - 1] * y[k - 1];
        q[4][k] = q[4][k - 1] + x[k + 8] * y[k + 8] - x[k - 1] * y[k - 1];
    }
}

__global__ void whsum5(const float* __restrict__ a, const float* __restrict__ b,
                       float* __restrict__ t0, float* __restrict__ t1,
                       float* __restrict__ t2, float* __restrict__ t3,
                       float* __restrict__ t4) {
    int t = blockIdx.x * 256 + threadIdx.x;
    int w = (t % W4) * 4;
    int d = (t / W4) % DD;
    int c = t / (W4 * DD);
    int h0 = c * HC;

    float S[5][4] = {{0}};
    // warm-up: rows h0-4 .. h0+4
    for (int j = 0; j < 9; j++) {
        int r = h0 - 4 + j;
        if ((unsigned)r < (unsigned)HHH) {
            float q[5][4];
            rowq5(a, b, (d * HHH + r) * WWW, w, q);
#pragma unroll
            for (int qq = 0; qq < 5; qq++)
#pragma unroll
                for (int k = 0; k < 4; k++) S[qq][k] += q[qq][k];
        }
    }
    {
        int idx = (d * HHH + h0) * WWW + w;
        *(float4*)(t0 + idx) = make_float4(S[0][0], S[0][1], S[0][2], S[0][3]);
        *(float4*)(t1 + idx) = make_float4(S[1][0], S[1][1], S[1][2], S[1][3]);
        *(float4*)(t2 + idx) = make_float4(S[2][0], S[2][1], S[2][2], S[2][3]);
        *(float4*)(t3 + idx) = make_float4(S[3][0], S[3][1], S[3][2], S[3][3]);
        *(float4*)(t4 + idx) = make_float4(S[4][0], S[4][1], S[4][2], S[4][3]);
    }
    for (int h = h0 + 1; h < h0 + HC; h++) {
        int rin = h + 4, rout = h - 5;
        if (rin < HHH) {
            float q[5][4];
            rowq5(a, b, (d * HHH + rin) * WWW, w, q);
#pragma unroll
            for (int qq = 0; qq < 5; qq++)
#pragma unroll
                for (int k = 0; k < 4; k++) S[qq][k] += q[qq][k];
        }
        if (rout >= 0) {
            float q[5][4];
            rowq5(a, b, (d * HHH + rout) * WWW, w, q);
#pragma unroll
            for (int qq = 0; qq < 5; qq++)
#pragma unroll
                for (int k = 0; k < 4; k++) S[qq][k] -= q[qq][k];
        }
        int idx = (d * HHH + h) * WWW + w;
        *(float4*)(t0 + idx) = make_float4(S[0][0], S[0][1], S[0][2], S[0][3]);
        *(float4*)(t1 + idx) = make_float4(S[1][0], S[1][1], S[1][2], S[1][3]);
        *(float4*)(t2 + idx) = make_float4(S[2][0], S[2][1], S[2][2], S[2][3]);
        *(float4*)(t3 + idx) = make_float4(S[3][0], S[3][1], S[3][2], S[3][3]);
        *(float4*)(t4 + idx) = make_float4(S[4][0], S[4][1], S[4][2], S[4][3]);
    }
}

// ---- D box-sum + cc + reduction, 4 outputs/thread, sliding D window --------
__device__ __forceinline__ float cc4(const float S[5][4]) {
    const float wsz = 729.0f;
    const float inv = 1.0f / 729.0f;
    float r = 0.f;
#pragma unroll
    for (int k = 0; k < 4; k++) {
        float uI = S[0][k] * inv;
        float uJ = S[1][k] * inv;
        float cross = S[4][k] - uJ * S[0][k] - uI * S[1][k] + uI * uJ * wsz;
        float Iv = S[2][k] - 2.0f * uI * S[0][k] + uI * uI * wsz;
        float Jv = S[3][k] - 2.0f * uJ * S[1][k] + uJ * uJ * wsz;
        r += cross * cross / (Iv * Jv + 1e-5f);
    }
    return r;
}

__global__ void dcc(const float* __restrict__ t0, const float* __restrict__ t1,
                    const float* __restrict__ t2, const float* __restrict__ t3,
                    const float* __restrict__ t4, double* __restrict__ acc, int pair) {
    int t = blockIdx.x * 256 + threadIdx.x;
    int w = (t % W4) * 4;
    int h = (t / W4) % HHH;
    int c = t / (W4 * HHH);
    int d0 = c * DC;

    float S[5][4] = {{0}};
    for (int j = 0; j < 9; j++) {
        int r = d0 - 4 + j;
        if ((unsigned)r < (unsigned)DD) {
            int idx = (r * HHH + h) * WWW + w;
            float4 v0 = *(const float4*)(t0 + idx);
            float4 v1 = *(const float4*)(t1 + idx);
            float4 v2 = *(const float4*)(t2 + idx);
            float4 v3 = *(const float4*)(t3 + idx);
            float4 v4 = *(const float4*)(t4 + idx);
            S[0][0] += v0.x; S[0][1] += v0.y; S[0][2] += v0.z; S[0][3] += v0.w;
            S[1][0] += v1.x; S[1][1] += v1.y; S[1][2] += v1.z; S[1][3] += v1.w;
            S[2][0] += v2.x; S[2][1] += v2.y; S[2][2] += v2.z; S[2][3] += v2.w;
            S[3][0] += v3.x; S[3][1] += v3.y; S[3][2] += v3.z; S[3][3] += v3.w;
            S[4][0] += v4.x; S[4][1] += v4.y; S[4][2] += v4.z; S[4][3] += v4.w;
        }
    }
    float local = cc4(S);
    for (int d = d0 + 1; d < d0 + DC; d++) {
        int rin = d + 4, rout = d - 5;
        if (rin < DD) {
            int idx = (rin * HHH + h) * WWW + w;
            float4 v0 = *(const float4*)(t0 + idx);
            float4 v1 = *(const float4*)(t1 + idx);
            float4 v2 = *(const float4*)(t2 + idx);
            float4 v3 = *(const float4*)(t3 + idx);
            float4 v4 = *(const float4*)(t4 + idx);
            S[0][0] += v0.x; S[0][1] += v0.y; S[0][2] += v0.z; S[0][3] += v0.w;
            S[1][0] += v1.x; S[1][1] += v1.y; S[1][2] += v1.z; S[1][3] += v1.w;
            S[2][0] += v2.x; S[2][1] += v2.y; S[2][2] += v2.z; S[2][3] += v2.w;
            S[3][0] += v3.x; S[3][1] += v3.y; S[3][2] += v3.z; S[3][3] += v3.w;
            S[4][0] += v4.x; S[4][1] += v4.y; S[4][2] += v4.z; S[4][3] += v4.w;
        }
        if (rout >= 0) {
            int idx = (rout * HHH + h) * WWW + w;
            float4 v0 = *(const float4*)(t0 + idx);
            float4 v1 = *(const float4*)(t1 + idx);
            float4 v2 = *(const float4*)(t2 + idx);
            float4 v3 = *(const float4*)(t3 + idx);
            float4 v4 = *(const float4*)(t4 + idx);
            S[0][0] -= v0.x; S[0][1] -= v0.y; S[0][2] -= v0.z; S[0][3] -= v0.w;
            S[1][0] -= v1.x; S[1][1] -= v1.y; S[1][2] -= v1.z; S[1][3] -= v1.w;
            S[2][0] -= v2.x; S[2][1] -= v2.y; S[2][2] -= v2.z; S[2][3] -= v2.w;
            S[3][0] -= v3.x; S[3][1] -= v3.y; S[3][2] -= v3.z; S[3][3] -= v3.w;
            S[4][0] -= v4.x; S[4][1] -= v4.y; S[4][2] -= v4.z; S[4][3] -= v4.w;
        }
        local += cc4(S);
    }

    for (int off = 32; off > 0; off >>= 1) local += __shfl_down(local, off);
    __shared__ float wsum_[4];
    if ((threadIdx.x & 63) == 0) wsum_[threadIdx.x >> 6] = local;
    __syncthreads();
    if (threadIdx.x == 0) {
        float s = wsum_[0] + wsum_[1] + wsum_[2] + wsum_[3];
        atomicAdd(&acc[pair], (double)s);
    }
}

__global__ void finalize_k(const double* __restrict__ acc, float* __restrict__ out) {
    if (threadIdx.x == 0) {
        double v = 0.8 * acc[0] + 0.1 * acc[1] + 0.1 * acc[2];
        out[0] = (float)(-v / (double)NV);
    }
}

extern "C" void kernel_launch(void* const* d_in, const int* in_sizes, int n_in,
                              void* d_out, int out_size, void* d_ws, size_t ws_size,
                              hipStream_t stream) {
    const float* yt = (const float*)d_in[0];
    const float* yp = (const float*)d_in[1];
    float* out = (float*)d_out;

    double* acc = (double*)d_ws;
    float* base = (float*)((char*)d_ws + 256);
    float* bufA = base;
    float* bufB = base + (size_t)NV;
    float* t0 = base + 2 * (size_t)NV;
    float* t1 = base + 3 * (size_t)NV;
    float* t2 = base + 4 * (size_t)NV;
    float* t3 = base + 5 * (size_t)NV;
    float* t4 = base + 6 * (size_t)NV;

    dim3 blk(256);
    dim3 grdE((NV / 4) / 256);                     // 4800 (stencils, 4-wide)
    dim3 grdWH((W4 * DD * (HHH / HC)) / 256);      // 800
    dim3 grdD((W4 * HHH * (DD / DC)) / 256);       // 960

    hipLaunchKernelGGL(zero_acc, dim3(1), dim3(64), 0, stream, acc);

    // pair 0: raw inputs
    hipLaunchKernelGGL(whsum5, grdWH, blk, 0, stream, yt, yp, t0, t1, t2, t3, t4);
    hipLaunchKernelGGL(dcc, grdD, blk, 0, stream, t0, t1, t2, t3, t4, acc, 0);

    // pair 1: Laplacian
    hipLaunchKernelGGL(lap4, grdE, blk, 0, stream, yt, yp, bufA, bufB);
    hipLaunchKernelGGL(whsum5, grdWH, blk, 0, stream, bufA, bufB, t0, t1, t2, t3, t4);
    hipLaunchKernelGGL(dcc, grdD, blk, 0, stream, t0, t1, t2, t3, t4, acc, 1);

    // pair 2: Sobel magnitude
    hipLaunchKernelGGL(sobel4, grdE, blk, 0, stream, yt, yp, bufA, bufB);
    hipLaunchKernelGGL(whsum5, grdWH, blk, 0, stream, bufA, bufB, t0, t1, t2, t3, t4);
    hipLaunchKernelGGL(dcc, grdD, blk, 0, stream, t0, t1, t2, t3, t4, acc, 2);

    hipLaunchKernelGGL(finalize_k, dim3(1), dim3(1), 0, stream, acc, out);
}

// Round 4
// 521.152 us; speedup vs baseline: 1.1747x; 1.1747x over previous
//
#include <hip/hip_runtime.h>
#include <math.h>

// Volume dims (1,1,160,192,160) fp32
#define DD 160
#define HHH 192
#define WWW 160
constexpr int HW = HHH * WWW;          // 30720
constexpr int NV = DD * HHH * WWW;     // 4915200
constexpr int W4 = WWW / 4;            // 40
constexpr int HC = 6;                  // whsum5 H-chunk: 192/6 = 32 chunks
constexpr int DC = 10;                 // dcc D-chunk: 160/10 = 16 chunks
constexpr int SC = 5;                  // sobel_ring D-chunk: 160/5 = 32 chunks

__global__ void zero_acc(double* __restrict__ acc) {
    if (threadIdx.x < 3) acc[threadIdx.x] = 0.0;
}

__device__ __forceinline__ float4 ldg4(const float* __restrict__ p, int idx, bool ok) {
    float4 z = make_float4(0.f, 0.f, 0.f, 0.f);
    return ok ? *(const float4*)(p + idx) : z;
}

// ---- Laplacian, 4 outputs/thread -------------------------------------------
__global__ void lap4(const float* __restrict__ a, const float* __restrict__ b,
                     float* __restrict__ oa, float* __restrict__ ob) {
    int t = blockIdx.x * 256 + threadIdx.x;
    int w = (t % W4) * 4;
    int h = (t / W4) % HHH;
    int d = t / (W4 * HHH);
    int idx = (d * HHH + h) * WWW + w;
    bool dok0 = d > 0, dok1 = d < DD - 1, hok0 = h > 0, hok1 = h < HHH - 1;

#pragma unroll
    for (int s = 0; s < 2; s++) {
        const float* p = s ? b : a;
        float* o = s ? ob : oa;
        float4 c = *(const float4*)(p + idx);
        float m1 = (w > 0) ? p[idx - 1] : 0.f;
        float p4 = (w + 4 < WWW) ? p[idx + 4] : 0.f;
        float4 dm = ldg4(p, idx - HW, dok0);
        float4 dp = ldg4(p, idx + HW, dok1);
        float4 hm = ldg4(p, idx - WWW, hok0);
        float4 hp = ldg4(p, idx + WWW, hok1);
        float4 r;
        r.x = 6.f * c.x - (m1 + c.y + dm.x + dp.x + hm.x + hp.x);
        r.y = 6.f * c.y - (c.x + c.z + dm.y + dp.y + hm.y + hp.y);
        r.z = 6.f * c.z - (c.y + c.w + dm.z + dp.z + hm.z + hp.z);
        r.w = 6.f * c.w - (c.z + p4 + dm.w + dp.w + hm.w + hp.w);
        *(float4*)(o + idx) = r;
    }
}

// ---- Sobel magnitude, d-marching ring, 4 outputs/thread --------------------
// Per slice s: A1 = sum_kh SM[kh]*gw  (gx = A1(d-1)+A1(d)+A1(d+1))
//              A2 = sum_kh    sw      (gy = A2(d+1)-A2(d-1))
//              A3 = sum_kh  kh*pw     (gz = A3(d-1)+2A3(d)+A3(d+1))
__device__ __forceinline__ void sobel_slice(const float* __restrict__ p, int s, int h, int w,
                                            float a1[4], float a2[4], float a3[4]) {
#pragma unroll
    for (int k = 0; k < 4; k++) { a1[k] = 0.f; a2[k] = 0.f; a3[k] = 0.f; }
#pragma unroll
    for (int kh = -1; kh <= 1; kh++) {
        int h2 = h + kh;
        if ((unsigned)h2 < (unsigned)HHH) {
            int rb = (s * HHH + h2) * WWW + w;
            float4 cen = *(const float4*)(p + rb);
            float xm = (w > 0) ? p[rb - 1] : 0.f;
            float xp = (w + 4 < WWW) ? p[rb + 4] : 0.f;
            float xv[6] = {xm, cen.x, cen.y, cen.z, cen.w, xp};
            float smh = (kh == 0) ? 2.f : 1.f;
            float grh = (float)kh;
#pragma unroll
            for (int k = 0; k < 4; k++) {
                float gw = xv[k + 2] - xv[k];
                float pw = xv[k] + xv[k + 1] + xv[k + 2];
                float sw = pw + xv[k + 1];
                a1[k] += smh * gw;
                a2[k] += sw;
                a3[k] += grh * pw;
            }
        }
    }
}

__global__ void sobel_ring(const float* __restrict__ a, const float* __restrict__ b,
                           float* __restrict__ oa, float* __restrict__ ob) {
    int t = blockIdx.x * 256 + threadIdx.x;
    int w = (t % W4) * 4;
    int h = (t / W4) % HHH;
    int c = t / (W4 * HHH);
    int d0 = c * SC;

    // ring slots: [0]=s-2, [1]=s-1, [2]=s  (fully unrolled -> renamed regs)
    float A1[2][3][4], A2[2][3][4], A3[2][3][4];
#pragma unroll
    for (int r = 0; r < 2; r++)
#pragma unroll
        for (int j = 0; j < 3; j++)
#pragma unroll
            for (int k = 0; k < 4; k++) { A1[r][j][k] = 0.f; A2[r][j][k] = 0.f; A3[r][j][k] = 0.f; }

#pragma unroll
    for (int i = 0; i < SC + 2; i++) {
        int s = d0 - 1 + i;
        // rotate
#pragma unroll
        for (int r = 0; r < 2; r++)
#pragma unroll
            for (int k = 0; k < 4; k++) {
                A1[r][0][k] = A1[r][1][k]; A2[r][0][k] = A2[r][1][k]; A3[r][0][k] = A3[r][1][k];
                A1[r][1][k] = A1[r][2][k]; A2[r][1][k] = A2[r][2][k]; A3[r][1][k] = A3[r][2][k];
            }
        if (s >= 0 && s < DD) {
            sobel_slice(a, s, h, w, A1[0][2], A2[0][2], A3[0][2]);
            sobel_slice(b, s, h, w, A1[1][2], A2[1][2], A3[1][2]);
        } else {
#pragma unroll
            for (int r = 0; r < 2; r++)
#pragma unroll
                for (int k = 0; k < 4; k++) { A1[r][2][k] = 0.f; A2[r][2][k] = 0.f; A3[r][2][k] = 0.f; }
        }
        if (i >= 2) {
            int d = s - 1;
            int idx = (d * HHH + h) * WWW + w;
            float4 ra, rb;
            float* pa = (float*)&ra;
            float* pb = (float*)&rb;
#pragma unroll
            for (int k = 0; k < 4; k++) {
                float gx = A1[0][0][k] + A1[0][1][k] + A1[0][2][k];
                float gy = A2[0][2][k] - A2[0][0][k];
                float gz = A3[0][0][k] + 2.f * A3[0][1][k] + A3[0][2][k];
                pa[k] = sqrtf(gx * gx + gy * gy + gz * gz);
                gx = A1[1][0][k] + A1[1][1][k] + A1[1][2][k];
                gy = A2[1][2][k] - A2[1][0][k];
                gz = A3[1][0][k] + 2.f * A3[1][1][k] + A3[1][2][k];
                pb[k] = sqrtf(gx * gx + gy * gy + gz * gz);
            }
            *(float4*)(oa + idx) = ra;
            *(float4*)(ob + idx) = rb;
        }
    }
}

// ---- Fused W+H box sums of 5 moments, 4 outputs/thread, sliding H window ----
__device__ __forceinline__ void rowq5(const float* __restrict__ a, const float* __restrict__ b,
                                      int rowbase, int w, float q[5][4]) {
    bool lo = (w >= 4);
    bool hi = (w + 7 < WWW);
    float4 x0 = ldg4(a, rowbase + w - 4, lo);
    float4 x1 = *(const float4*)(a + rowbase + w);
    float4 x2 = ldg4(a, rowbase + w + 4, hi);
    float4 y0 = ldg4(b, rowbase + w - 4, lo);
    float4 y1 = *(const float4*)(b + rowbase + w);
    float4 y2 = ldg4(b, rowbase + w + 4, hi);
    float x[12] = {x0.x, x0.y, x0.z, x0.w, x1.x, x1.y, x1.z, x1.w, x2.x, x2.y, x2.z, x2.w};
    float y[12] = {y0.x, y0.y, y0.z, y0.w, y1.x, y1.y, y1.z, y1.w, y2.x, y2.y, y2.z, y2.w};
    float s0 = 0, s1 = 0, s2 = 0, s3 = 0, s4 = 0;
#pragma unroll
    for (int j = 0; j < 9; j++) {
        s0 += x[j]; s1 += y[j];
        s2 += x[j] * x[j]; s3 += y[j] * y[j]; s4 += x[j] * y[j];
    }
    q[0][0] = s0; q[1][0] = s1; q[2][0] = s2; q[3][0] = s3; q[4][0] = s4;
#pragma unroll
    for (int k = 1; k < 4; k++) {
        q[0][k] = q[0][k - 1] + x[k + 8] - x[k - 1];
        q[1][k] = q[1][k - 1] + y[k + 8] - y[k - 1];
        q[2][k] = q[2][k - 1] + x[k + 8] * x[k + 8] - x[k - 1] * x[k - 1];
        q[3][k] = q[3][k - 1] + y[k + 8] * y[k + 8] - y[k - 1] * y[k - 1];
        q[4][k] = q[4][k - 1] + x[k + 8] * y[k + 8] - x[k - 1] * y[k - 1];
    }
}

__global__ void whsum5(const float* __restrict__ a, const float* __restrict__ b,
                       float* __restrict__ t0, float* __restrict__ t1,
                       float* __restrict__ t2, float* __restrict__ t3,
                       float* __restrict__ t4) {
    int t = blockIdx.x * 256 + threadIdx.x;
    int w = (t % W4) * 4;
    int d = (t / W4) % DD;
    int c = t / (W4 * DD);
    int h0 = c * HC;

    float S[5][4] = {{0}};
    for (int j = 0; j < 9; j++) {
        int r = h0 - 4 + j;
        if ((unsigned)r < (unsigned)HHH) {
            float q[5][4];
            rowq5(a, b, (d * HHH + r) * WWW, w, q);
#pragma unroll
            for (int qq = 0; qq < 5; qq++)
#pragma unroll
                for (int k = 0; k < 4; k++) S[qq][k] += q[qq][k];
        }
    }
    {
        int idx = (d * HHH + h0) * WWW + w;
        *(float4*)(t0 + idx) = make_float4(S[0][0], S[0][1], S[0][2], S[0][3]);
        *(float4*)(t1 + idx) = make_float4(S[1][0], S[1][1], S[1][2], S[1][3]);
        *(float4*)(t2 + idx) = make_float4(S[2][0], S[2][1], S[2][2], S[2][3]);
        *(float4*)(t3 + idx) = make_float4(S[3][0], S[3][1], S[3][2], S[3][3]);
        *(float4*)(t4 + idx) = make_float4(S[4][0], S[4][1], S[4][2], S[4][3]);
    }
    for (int h = h0 + 1; h < h0 + HC; h++) {
        int rin = h + 4, rout = h - 5;
        if (rin < HHH) {
            float q[5][4];
            rowq5(a, b, (d * HHH + rin) * WWW, w, q);
#pragma unroll
            for (int qq = 0; qq < 5; qq++)
#pragma unroll
                for (int k = 0; k < 4; k++) S[qq][k] += q[qq][k];
        }
        if (rout >= 0) {
            float q[5][4];
            rowq5(a, b, (d * HHH + rout) * WWW, w, q);
#pragma unroll
            for (int qq = 0; qq < 5; qq++)
#pragma unroll
                for (int k = 0; k < 4; k++) S[qq][k] -= q[qq][k];
        }
        int idx = (d * HHH + h) * WWW + w;
        *(float4*)(t0 + idx) = make_float4(S[0][0], S[0][1], S[0][2], S[0][3]);
        *(float4*)(t1 + idx) = make_float4(S[1][0], S[1][1], S[1][2], S[1][3]);
        *(float4*)(t2 + idx) = make_float4(S[2][0], S[2][1], S[2][2], S[2][3]);
        *(float4*)(t3 + idx) = make_float4(S[3][0], S[3][1], S[3][2], S[3][3]);
        *(float4*)(t4 + idx) = make_float4(S[4][0], S[4][1], S[4][2], S[4][3]);
    }
}

// ---- D box-sum + cc + reduction, scalar, sliding D window ------------------
__device__ __forceinline__ float cc1(float s0, float s1, float s2, float s3, float s4) {
    const float wsz = 729.0f;
    const float inv = 1.0f / 729.0f;
    float uI = s0 * inv;
    float uJ = s1 * inv;
    float cross = s4 - uJ * s0 - uI * s1 + uI * uJ * wsz;
    float Iv = s2 - 2.0f * uI * s0 + uI * uI * wsz;
    float Jv = s3 - 2.0f * uJ * s1 + uJ * uJ * wsz;
    return cross * cross / (Iv * Jv + 1e-5f);
}

__global__ void dcc(const float* __restrict__ t0, const float* __restrict__ t1,
                    const float* __restrict__ t2, const float* __restrict__ t3,
                    const float* __restrict__ t4, double* __restrict__ acc, int pair) {
    int t = blockIdx.x * 256 + threadIdx.x;
    int w = t % WWW;
    int h = (t / WWW) % HHH;
    int c = t / HW;
    int d0 = c * DC;

    float S0 = 0, S1 = 0, S2 = 0, S3 = 0, S4 = 0;
    for (int j = 0; j < 9; j++) {
        int r = d0 - 4 + j;
        if ((unsigned)r < (unsigned)DD) {
            int idx = (r * HHH + h) * WWW + w;
            S0 += t0[idx]; S1 += t1[idx]; S2 += t2[idx]; S3 += t3[idx]; S4 += t4[idx];
        }
    }
    float local = cc1(S0, S1, S2, S3, S4);
    for (int d = d0 + 1; d < d0 + DC; d++) {
        int rin = d + 4, rout = d - 5;
        if (rin < DD) {
            int idx = (rin * HHH + h) * WWW + w;
            S0 += t0[idx]; S1 += t1[idx]; S2 += t2[idx]; S3 += t3[idx]; S4 += t4[idx];
        }
        if (rout >= 0) {
            int idx = (rout * HHH + h) * WWW + w;
            S0 -= t0[idx]; S1 -= t1[idx]; S2 -= t2[idx]; S3 -= t3[idx]; S4 -= t4[idx];
        }
        local += cc1(S0, S1, S2, S3, S4);
    }

    for (int off = 32; off > 0; off >>= 1) local += __shfl_down(local, off);
    __shared__ float wsum_[4];
    if ((threadIdx.x & 63) == 0) wsum_[threadIdx.x >> 6] = local;
    __syncthreads();
    if (threadIdx.x == 0) {
        float s = wsum_[0] + wsum_[1] + wsum_[2] + wsum_[3];
        atomicAdd(&acc[pair], (double)s);
    }
}

__global__ void finalize_k(const double* __restrict__ acc, float* __restrict__ out) {
    if (threadIdx.x == 0) {
        double v = 0.8 * acc[0] + 0.1 * acc[1] + 0.1 * acc[2];
        out[0] = (float)(-v / (double)NV);
    }
}

extern "C" void kernel_launch(void* const* d_in, const int* in_sizes, int n_in,
                              void* d_out, int out_size, void* d_ws, size_t ws_size,
                              hipStream_t stream) {
    const float* yt = (const float*)d_in[0];
    const float* yp = (const float*)d_in[1];
    float* out = (float*)d_out;

    double* acc = (double*)d_ws;
    float* base = (float*)((char*)d_ws + 256);
    float* bufA = base;
    float* bufB = base + (size_t)NV;
    float* t0 = base + 2 * (size_t)NV;
    float* t1 = base + 3 * (size_t)NV;
    float* t2 = base + 4 * (size_t)NV;
    float* t3 = base + 5 * (size_t)NV;
    float* t4 = base + 6 * (size_t)NV;

    dim3 blk(256);
    dim3 grdE((NV / 4) / 256);                     // 4800 (lap4)
    dim3 grdS((W4 * HHH * (DD / SC)) / 256);       // 960  (sobel_ring)
    dim3 grdWH((W4 * DD * (HHH / HC)) / 256);      // 800
    dim3 grdD((WWW * HHH * (DD / DC)) / 256);      // 1920

    hipLaunchKernelGGL(zero_acc, dim3(1), dim3(64), 0, stream, acc);

    // pair 0: raw inputs
    hipLaunchKernelGGL(whsum5, grdWH, blk, 0, stream, yt, yp, t0, t1, t2, t3, t4);
    hipLaunchKernelGGL(dcc, grdD, blk, 0, stream, t0, t1, t2, t3, t4, acc, 0);

    // pair 1: Laplacian
    hipLaunchKernelGGL(lap4, grdE, blk, 0, stream, yt, yp, bufA, bufB);
    hipLaunchKernelGGL(whsum5, grdWH, blk, 0, stream, bufA, bufB, t0, t1, t2, t3, t4);
    hipLaunchKernelGGL(dcc, grdD, blk, 0, stream, t0, t1, t2, t3, t4, acc, 1);

    // pair 2: Sobel magnitude
    hipLaunchKernelGGL(sobel_ring, grdS, blk, 0, stream, yt, yp, bufA, bufB);
    hipLaunchKernelGGL(whsum5, grdWH, blk, 0, stream, bufA, bufB, t0, t1, t2, t3, t4);
    hipLaunchKernelGGL(dcc, grdD, blk, 0, stream, t0, t1, t2, t3, t4, acc, 2);

    hipLaunchKernelGGL(finalize_k, dim3(1), dim3(1), 0, stream, acc, out);
}